// Round 2
// baseline (1569.667 us; speedup 1.0000x reference)
//
#include <hip/hip_runtime.h>

// Round 2 (resubmit of R1 after GPU timeout; desk-verified, no logic changes):
// fused window-attention (LSA/Swin-style), split-bf16 MFMA everywhere.
// N=49 tokens, C=256, H=8 heads, HD=32, BW=4096 windows, NW=64.
// One 512-thread block (8 waves) per window. 126KiB static LDS, phase-overlaid.

typedef unsigned short u16;
typedef unsigned int   u32;
typedef __attribute__((ext_vector_type(8))) short bf16x8;
typedef __attribute__((ext_vector_type(4))) float f32x4;

#define MFMA(a,b,c) __builtin_amdgcn_mfma_f32_16x16x32_bf16((a),(b),(c),0,0,0)

__device__ __forceinline__ u16 bf_hi(float f){
  u32 u = __float_as_uint(f);
  u += 0x7FFFu + ((u >> 16) & 1u);          // RNE to bf16
  return (u16)(u >> 16);
}
__device__ __forceinline__ float bf_f(u16 h){ return __uint_as_float(((u32)h) << 16); }

union U8 { bf16x8 v; u16 e[8]; };

// ---------------- weight/bias packing prologue ----------------
// ws layout (bytes):
//   [0, 786432)        wsQKV: 16 chunks of 49152B = (grp,kp) x {hi[2kcL][12tile][64lane][8], lo[...]}
//   [786432, 917504)   wsPROJ_HI: [h8][nt16][lane64][8] u16
//   [917504, 1048576)  wsPROJ_LO
//   [1048576, 1125408) biasws: [8][49][49] f32
__global__ void wa_pack(const float* __restrict__ qkv_w, const float* __restrict__ proj_w,
                        const float* __restrict__ rpb,
                        u16* __restrict__ wQ, u16* __restrict__ wPH, u16* __restrict__ wPL,
                        float* __restrict__ biasws)
{
  int tid = blockIdx.x * 256 + threadIdx.x;
  if (tid < 196608){
    int t0 = tid;
    int chunk = t0 / 12288, rem = t0 % 12288;
    int kcL = rem / 6144, rem2 = rem % 6144;
    int tile = rem2 / 512, rem3 = rem2 % 512;
    int lane = rem3 >> 3, j = rem3 & 7;
    int grp = chunk >> 2, kp = chunk & 3, kc = kp*2 + kcL;
    int hh = tile / 6, t6 = tile % 6, tt = t6 >> 1, nt = t6 & 1;
    int kg  = kc*32 + (lane>>4)*8 + j;                       // contraction index (C)
    int col = tt*256 + (grp*2+hh)*32 + nt*16 + (lane&15);    // d in [0,768): qkv,h,hd
    float f = qkv_w[kg*768 + col];
    u16 hi = bf_hi(f), lo = bf_hi(f - bf_f(hi));
    int base = chunk*24576 + kcL*6144 + tile*512 + lane*8 + j;
    wQ[base] = hi; wQ[base + 12288] = lo;
  } else if (tid < 262144){
    int t1 = tid - 196608;
    int j = t1 & 7, lane = (t1>>3)&63, nt = (t1>>9)&15, h = t1>>13;
    int kg  = h*32 + (lane>>4)*8 + j;
    int col = nt*16 + (lane&15);
    float f = proj_w[kg*256 + col];
    u16 hi = bf_hi(f), lo = bf_hi(f - bf_f(hi));
    wPH[t1] = hi; wPL[t1] = lo;
  } else if (tid < 281352){
    int t2 = tid - 262144;
    int h = t2 / 2401, r = t2 % 2401;
    int i = r / 49, jj = r % 49;
    int ih = i/7, iw = i%7, jh = jj/7, jw = jj%7;
    int idx = (ih - jh + 6)*13 + (iw - jw + 6);
    biasws[t2] = rpb[idx*8 + h];
  }
}

// ---------------- main fused kernel ----------------
// LDS map (129024B static, phase-overlaid; all b128 targets 16B-aligned):
//   [0,49152)       Wstage slot0 | Pbuf hi[8][16][72] @0 + lo @18432 (attn phase) | x-staging head
//   [49152,98304)   Wstage slot1 (QKV phase only; overlays qkvbuf start)
//   [49152,108544)  qkvbuf: qhi/qlo [2][64][40], khi/klo [2][64][40], vthi/vtlo [2][32][72]
//   [108544,129024) obuf: ohi/olo [2][64][40]
__global__ __launch_bounds__(512, 2) void wa_main(
    const float* __restrict__ x, const float* __restrict__ mask,
    const float* __restrict__ temp,
    const u16* __restrict__ wQ, const u16* __restrict__ wPH, const u16* __restrict__ wPL,
    const float* __restrict__ biasws, const float* __restrict__ proj_b,
    float* __restrict__ out)
{
  __shared__ __align__(16) char LDSB[129024];
  float* xs  = (float*)LDSB;                 // [64][260] fp32 staging (transient)
  u16* wst   = (u16*)LDSB;                   // Wstage (u16 offsets 0 / 24576)
  u16* Phi   = (u16*)LDSB;                   // [8][16][72]
  u16* Plo   = (u16*)(LDSB + 18432);
  u16* qhi   = (u16*)(LDSB + 49152);         // [2][64][40]
  u16* qlo   = (u16*)(LDSB + 59392);
  u16* khi   = (u16*)(LDSB + 69632);
  u16* klo   = (u16*)(LDSB + 79872);
  u16* vthi  = (u16*)(LDSB + 90112);         // [2][32][72] (v transposed)
  u16* vtlo  = (u16*)(LDSB + 99328);
  u16* ohi   = (u16*)(LDSB + 108544);        // [2][64][40]
  u16* olo   = (u16*)(LDSB + 118784);

  const int tid = threadIdx.x;
  const int w = tid >> 6, lane = tid & 63;
  const int p = lane & 15, lg = lane >> 4;
  const int mt = w & 3;        // row-tile owned (QKV + attention + epilogue)
  const int hh = w >> 2;       // head-in-group owned (QKV + attention)
  const int b  = blockIdx.x;
  const float scale = __expf(temp[0]);

  // ---- stage x window into LDS (rows>=49 zeroed; pad 260 -> 2-way banks) ----
  {
    const float* xb = x + (size_t)b * 12544;
    #pragma unroll
    for (int it = 0; it < 8; ++it){
      int fid = it*512 + tid;
      int row = fid >> 6, c4 = (fid & 63) << 2;
      float4 v = make_float4(0.f, 0.f, 0.f, 0.f);
      if (row < 49) v = *(const float4*)(xb + row*256 + c4);
      *(float4*)(xs + row*260 + c4) = v;
    }
  }
  __syncthreads();

  // ---- per-wave x A-fragments, split hi/lo (A[p][8*lg+j], k=kc*32+8*lg+j) ----
  U8 axh[8], axl[8];
  {
    const int row = mt*16 + p;
    #pragma unroll
    for (int kc = 0; kc < 8; ++kc){
      float4 f0 = *(const float4*)(xs + row*260 + kc*32 + lg*8);
      float4 f1 = *(const float4*)(xs + row*260 + kc*32 + lg*8 + 4);
      float ff[8] = {f0.x,f0.y,f0.z,f0.w,f1.x,f1.y,f1.z,f1.w};
      #pragma unroll
      for (int j = 0; j < 8; ++j){
        u16 h = bf_hi(ff[j]);
        axh[kc].e[j] = h;
        axl[kc].e[j] = bf_hi(ff[j] - bf_f(h));
      }
    }
  }
  __syncthreads();   // xs region free (reused by Wstage/Pbuf)

  const f32x4 z4 = {0.f, 0.f, 0.f, 0.f};
  f32x4 pacc[4][2];
  #pragma unroll
  for (int m2 = 0; m2 < 4; ++m2){ pacc[m2][0] = z4; pacc[m2][1] = z4; }

  for (int grp = 0; grp < 4; ++grp){
    const int h = grp*2 + hh;

    // ================= QKV GEMM (LDS-dbuf weight chunks) =================
    f32x4 qa[2], ka[2], va[2];
    #pragma unroll
    for (int n = 0; n < 2; ++n){ qa[n] = z4; ka[n] = z4; va[n] = z4; }

    const u16* wg = wQ + (size_t)grp * 4 * 24576;
    { // chunk 0 -> slot0
      const float4* src = (const float4*)wg;
      float4* dst = (float4*)LDSB;
      #pragma unroll
      for (int i = 0; i < 6; ++i) dst[tid + i*512] = src[tid + i*512];
    }
    __syncthreads();
    #pragma unroll
    for (int kp = 0; kp < 4; ++kp){
      float4 pf[6];
      if (kp < 3){
        const float4* src = (const float4*)(wg + (kp+1)*24576);
        #pragma unroll
        for (int i = 0; i < 6; ++i) pf[i] = src[tid + i*512];
      }
      const int slot = (kp & 1) * 24576;
      #pragma unroll
      for (int kcL = 0; kcL < 2; ++kcL){
        const int kc = kp*2 + kcL;
        #pragma unroll
        for (int tt = 0; tt < 3; ++tt){
          #pragma unroll
          for (int n = 0; n < 2; ++n){
            const u16* ph = wst + slot + kcL*6144 + (hh*6 + tt*2 + n)*512 + lane*8;
            bf16x8 bh = *(const bf16x8*)ph;
            bf16x8 bl = *(const bf16x8*)(ph + 12288);
            f32x4 acc = (tt==0) ? qa[n] : (tt==1) ? ka[n] : va[n];
            acc = MFMA(axh[kc].v, bh, acc);
            acc = MFMA(axh[kc].v, bl, acc);
            acc = MFMA(axl[kc].v, bh, acc);
            if (tt==0) qa[n] = acc; else if (tt==1) ka[n] = acc; else va[n] = acc;
          }
        }
      }
      if (kp < 3){
        float4* dst = (float4*)(LDSB + (size_t)((kp+1)&1) * 49152);
        #pragma unroll
        for (int i = 0; i < 6; ++i) dst[tid + i*512] = pf[i];
      }
      __syncthreads();
    }

    // ---- bias + shift-mask prefetch (L2/L3-hot gathers) ----
    float bm[4][4];
    {
      const int wi = b & 63;
      #pragma unroll
      for (int n = 0; n < 4; ++n){
        #pragma unroll
        for (int r = 0; r < 4; ++r){
          const int i = mt*16 + lg*4 + r, j = n*16 + p;
          float v = 0.f;
          if (i < 49 && j < 49)
            v = biasws[h*2401 + i*49 + j] + mask[wi*2401 + i*49 + j];
          bm[n][r] = v;
        }
      }
    }

    // ---- bounce q,k (row-major [64][40]) and v (transposed [32][72]) ----
    #pragma unroll
    for (int n = 0; n < 2; ++n){
      #pragma unroll
      for (int r = 0; r < 4; ++r){
        const int token = mt*16 + lg*4 + r, dim = n*16 + p;
        const int qk = hh*2560 + token*40 + dim;
        float qv = qa[n][r]; u16 qh_ = bf_hi(qv);
        qhi[qk] = qh_; qlo[qk] = bf_hi(qv - bf_f(qh_));
        float kv = ka[n][r]; u16 kh_ = bf_hi(kv);
        khi[qk] = kh_; klo[qk] = bf_hi(kv - bf_f(kh_));
        const int vk = hh*2304 + dim*72 + token;
        float vv = va[n][r]; u16 vh_ = bf_hi(vv);
        vthi[vk] = vh_; vtlo[vk] = bf_hi(vv - bf_f(vh_));
      }
    }
    __syncthreads();

    // ================= S = q k^T (scaled), + bias/mask, LSA diag =================
    U8 qfh, qfl;
    qfh.v = *(const bf16x8*)(qhi + hh*2560 + (mt*16 + p)*40 + lg*8);
    qfl.v = *(const bf16x8*)(qlo + hh*2560 + (mt*16 + p)*40 + lg*8);
    f32x4 sa[4];
    #pragma unroll
    for (int n = 0; n < 4; ++n) sa[n] = z4;
    #pragma unroll
    for (int n = 0; n < 4; ++n){
      bf16x8 kfh = *(const bf16x8*)(khi + hh*2560 + (n*16 + p)*40 + lg*8);
      bf16x8 kfl = *(const bf16x8*)(klo + hh*2560 + (n*16 + p)*40 + lg*8);
      sa[n] = MFMA(qfh.v, kfh, sa[n]);
      sa[n] = MFMA(qfh.v, kfl, sa[n]);
      sa[n] = MFMA(qfl.v, kfh, sa[n]);
    }

    // ---- softmax over 64 cols (16 p-lanes x 4 n-tiles); normalization deferred ----
    float pr[4][4], rinv[4];
    #pragma unroll
    for (int r = 0; r < 4; ++r){
      const int i = mt*16 + lg*4 + r;
      float mx = -3.0e38f;
      #pragma unroll
      for (int n = 0; n < 4; ++n){
        const int j = n*16 + p;
        float s = sa[n][r]*scale + bm[n][r];
        if (j >= 49 || j == i) s = -3.0e38f;   // pad cols + LSA diagonal
        pr[n][r] = s;
        mx = fmaxf(mx, s);
      }
      mx = fmaxf(mx, __shfl_xor(mx, 1));
      mx = fmaxf(mx, __shfl_xor(mx, 2));
      mx = fmaxf(mx, __shfl_xor(mx, 4));
      mx = fmaxf(mx, __shfl_xor(mx, 8));
      float sum = 0.f;
      #pragma unroll
      for (int n = 0; n < 4; ++n){
        float e = __expf(pr[n][r] - mx);
        pr[n][r] = e; sum += e;
      }
      sum += __shfl_xor(sum, 1);
      sum += __shfl_xor(sum, 2);
      sum += __shfl_xor(sum, 4);
      sum += __shfl_xor(sum, 8);
      rinv[r] = 1.0f / sum;
    }

    // ---- P bounce (wave-private [16][72], hi/lo) ----
    #pragma unroll
    for (int n = 0; n < 4; ++n){
      #pragma unroll
      for (int r = 0; r < 4; ++r){
        const int idx = w*1152 + (lg*4 + r)*72 + n*16 + p;
        float pv = pr[n][r]; u16 ph_ = bf_hi(pv);
        Phi[idx] = ph_; Plo[idx] = bf_hi(pv - bf_f(ph_));
      }
    }
    __syncthreads();

    // ================= O = P V =================
    f32x4 oa[2]; oa[0] = z4; oa[1] = z4;
    #pragma unroll
    for (int kc = 0; kc < 2; ++kc){
      U8 pfh, pfl;
      pfh.v = *(const bf16x8*)(Phi + w*1152 + p*72 + kc*32 + lg*8);
      pfl.v = *(const bf16x8*)(Plo + w*1152 + p*72 + kc*32 + lg*8);
      #pragma unroll
      for (int n = 0; n < 2; ++n){
        bf16x8 vfh = *(const bf16x8*)(vthi + hh*2304 + (n*16 + p)*72 + kc*32 + lg*8);
        bf16x8 vfl = *(const bf16x8*)(vtlo + hh*2304 + (n*16 + p)*72 + kc*32 + lg*8);
        oa[n] = MFMA(pfh.v, vfh, oa[n]);
        oa[n] = MFMA(pfh.v, vfl, oa[n]);
        oa[n] = MFMA(pfl.v, vfh, oa[n]);
      }
    }
    // ---- O bounce (apply deferred 1/sum) ----
    #pragma unroll
    for (int n = 0; n < 2; ++n){
      #pragma unroll
      for (int r = 0; r < 4; ++r){
        const int token = mt*16 + lg*4 + r, dim = n*16 + p;
        const int ok = hh*2560 + token*40 + dim;
        float ov = oa[n][r] * rinv[r];
        u16 oh_ = bf_hi(ov);
        ohi[ok] = oh_; olo[ok] = bf_hi(ov - bf_f(oh_));
      }
    }
    __syncthreads();

    // ================= proj accumulate (N-split: wave owns cols [32w,32w+32)) =================
    #pragma unroll
    for (int hc = 0; hc < 2; ++hc){
      const int hg = grp*2 + hc;
      U8 ah[4], al[4];
      #pragma unroll
      for (int m2 = 0; m2 < 4; ++m2){
        ah[m2].v = *(const bf16x8*)(ohi + hc*2560 + (m2*16 + p)*40 + lg*8);
        al[m2].v = *(const bf16x8*)(olo + hc*2560 + (m2*16 + p)*40 + lg*8);
      }
      #pragma unroll
      for (int n = 0; n < 2; ++n){
        const u16* bp = wPH + ((size_t)(hg*16 + w*2 + n)*64 + lane)*8;
        bf16x8 bh = *(const bf16x8*)bp;
        bf16x8 bl = *(const bf16x8*)(wPL + ((size_t)(hg*16 + w*2 + n)*64 + lane)*8);
        #pragma unroll
        for (int m2 = 0; m2 < 4; ++m2){
          pacc[m2][n] = MFMA(ah[m2].v, bh, pacc[m2][n]);
          pacc[m2][n] = MFMA(ah[m2].v, bl, pacc[m2][n]);
          pacc[m2][n] = MFMA(al[m2].v, bh, pacc[m2][n]);
        }
      }
    }
    __syncthreads();   // frees obuf/Pbuf/Wstage regions for next group
  }

  // ================= epilogue: + proj_b, store =================
  const float pb0 = proj_b[(w*2 + 0)*16 + p];
  const float pb1 = proj_b[(w*2 + 1)*16 + p];
  #pragma unroll
  for (int m2 = 0; m2 < 4; ++m2){
    #pragma unroll
    for (int r = 0; r < 4; ++r){
      const int row = m2*16 + lg*4 + r;
      if (row < 49){
        float* o = out + (size_t)b*12544 + row*256 + (w*2)*16 + p;
        o[0]  = pacc[m2][0][r] + pb0;
        o[16] = pacc[m2][1][r] + pb1;
      }
    }
  }
}

extern "C" void kernel_launch(void* const* d_in, const int* in_sizes, int n_in,
                              void* d_out, int out_size, void* d_ws, size_t ws_size,
                              hipStream_t stream)
{
  (void)in_sizes; (void)n_in; (void)out_size; (void)ws_size;
  const float* x      = (const float*)d_in[0];
  const float* mask   = (const float*)d_in[1];
  const float* qkv_w  = (const float*)d_in[2];
  const float* proj_w = (const float*)d_in[3];
  const float* proj_b = (const float*)d_in[4];
  const float* rpb    = (const float*)d_in[5];
  const float* temp   = (const float*)d_in[6];

  u16*   wQ     = (u16*)d_ws;
  u16*   wPH    = (u16*)((char*)d_ws + 786432);
  u16*   wPL    = (u16*)((char*)d_ws + 917504);
  float* biasws = (float*)((char*)d_ws + 1048576);

  wa_pack<<<1100, 256, 0, stream>>>(qkv_w, proj_w, rpb, wQ, wPH, wPL, biasws);
  wa_main<<<4096, 512, 0, stream>>>(x, mask, temp, wQ, wPH, wPL, biasws, proj_b,
                                    (float*)d_out);
}

// Round 4
// 1080.665 us; speedup vs baseline: 1.4525x; 1.4525x over previous
//
#include <hip/hip_runtime.h>

// Round 4 (resubmit of R3 after GPU timeout; desk-verified, no logic changes):
//  - plain bf16 QKV GEMM + attention (was 3-MFMA split): MFMA/wave-grp 216->104
//  - proj GEMM keeps double split (O and W hi/lo) to shave final error
//  - LDS 129KB -> 68.6KB (Wstage single-buffer, hi-only; overlaid attn bufs)
//  - weight staging via global_load_lds width=16 (zero staging VGPRs)
//  - __launch_bounds__(512,4): 4 waves/SIMD = 2 blocks/CU
// Risk: absmax rises ~2.4e-4 -> ~3e-3 (threshold unknown; fallback plan ready).

typedef unsigned short u16;
typedef unsigned int   u32;
typedef __attribute__((ext_vector_type(8))) short bf16x8;
typedef __attribute__((ext_vector_type(4))) float f32x4;

#define MFMA(a,b,c) __builtin_amdgcn_mfma_f32_16x16x32_bf16((a),(b),(c),0,0,0)

__device__ __forceinline__ u16 bf_hi(float f){
  u32 u = __float_as_uint(f);
  u += 0x7FFFu + ((u >> 16) & 1u);          // RNE to bf16
  return (u16)(u >> 16);
}
__device__ __forceinline__ float bf_f(u16 h){ return __uint_as_float(((u32)h) << 16); }

union U8 { bf16x8 v; u16 e[8]; };

// async global->LDS, 16B/lane. l = wave-uniform LDS base (HW adds lane*16),
// g = per-lane global pointer.
__device__ __forceinline__ void gload16(const void* g, void* l){
  __builtin_amdgcn_global_load_lds((const __attribute__((address_space(1))) void*)g,
                                   (__attribute__((address_space(3))) void*)l, 16, 0, 0);
}

// ---------------- weight/bias packing prologue ----------------
// ws layout (bytes):
//   [0, 393216)        wQ:  16 chunks of 24576B = (grp,kp) x [kcL2][tile12][lane64][j8] bf16-hi
//   [393216, 524288)   wPH: [h8][nt16][lane64][8] u16 (proj hi)
//   [524288, 655360)   wPL: proj lo
//   [655360, 732192)   biasws: [8][49][49] f32
__global__ void wa_pack(const float* __restrict__ qkv_w, const float* __restrict__ proj_w,
                        const float* __restrict__ rpb,
                        u16* __restrict__ wQ, u16* __restrict__ wPH, u16* __restrict__ wPL,
                        float* __restrict__ biasws)
{
  int tid = blockIdx.x * 256 + threadIdx.x;
  if (tid < 196608){
    int chunk = tid / 12288, rem = tid % 12288;
    int kcL = rem / 6144, rem2 = rem % 6144;
    int tile = rem2 / 512, rem3 = rem2 % 512;
    // lane16 fastest -> consecutive threads read consecutive cols (coalesced)
    int lane16 = rem3 & 15, j = (rem3 >> 4) & 7, lg = rem3 >> 7;
    int lane = lg*16 + lane16;
    int grp = chunk >> 2, kp = chunk & 3, kc = kp*2 + kcL;
    int kg  = kc*32 + lg*8 + j;                              // contraction index (C)
    int hh = tile / 6, t6 = tile % 6, tt = t6 >> 1, nt = t6 & 1;
    int col = tt*256 + (grp*2+hh)*32 + nt*16 + lane16;       // d in [0,768)
    float f = qkv_w[kg*768 + col];
    wQ[chunk*12288 + kcL*6144 + tile*512 + lane*8 + j] = bf_hi(f);
  } else if (tid < 262144){
    int t1 = tid - 196608;
    int j = t1 & 7, lane = (t1>>3)&63, nt = (t1>>9)&15, h = t1>>13;
    int kg  = h*32 + (lane>>4)*8 + j;
    int col = nt*16 + (lane&15);
    float f = proj_w[kg*256 + col];
    u16 hi = bf_hi(f), lo = bf_hi(f - bf_f(hi));
    wPH[t1] = hi; wPL[t1] = lo;
  } else if (tid < 281352){
    int t2 = tid - 262144;
    int h = t2 / 2401, r = t2 % 2401;
    int i = r / 49, jj = r % 49;
    int ih = i/7, iw = i%7, jh = jj/7, jw = jj%7;
    int idx = (ih - jh + 6)*13 + (iw - jw + 6);
    biasws[t2] = rpb[idx*8 + h];
  }
}

// ---------------- main fused kernel ----------------
// LDS map (68608B, phase-overlaid):
//   [0,24576)       Wstage (QKV phase)      | Phi [8][16][72] @0 (attn phase)
//   [18432,38912)   ohi [2][64][40] @18432, olo @28672 (post-PV)
//   [38912,68608)   qhi [2][64][40] @38912, khi @49152, vthi [2][32][72] @59392
//   [0,66560)       xs [64][260] f32 (prologue only)
__global__ __launch_bounds__(512, 4) void wa_main(
    const float* __restrict__ x, const float* __restrict__ mask,
    const float* __restrict__ temp,
    const u16* __restrict__ wQ, const u16* __restrict__ wPH, const u16* __restrict__ wPL,
    const float* __restrict__ biasws, const float* __restrict__ proj_b,
    float* __restrict__ out)
{
  __shared__ __align__(16) char LDSB[68608];
  float* xs  = (float*)LDSB;                 // [64][260] fp32 staging (transient)
  u16* wst   = (u16*)LDSB;                   // Wstage (12288 u16)
  u16* Phi   = (u16*)LDSB;                   // [8][16][72]
  u16* ohi   = (u16*)(LDSB + 18432);         // [2][64][40]
  u16* olo   = (u16*)(LDSB + 28672);
  u16* qhi   = (u16*)(LDSB + 38912);         // [2][64][40]
  u16* khi   = (u16*)(LDSB + 49152);
  u16* vthi  = (u16*)(LDSB + 59392);         // [2][32][72] (v transposed)

  const int tid = threadIdx.x;
  const int w = tid >> 6, lane = tid & 63;
  const int p = lane & 15, lg = lane >> 4;
  const int mt = w & 3;        // row-tile owned
  const int hh = w >> 2;       // head-in-group owned
  const int b  = blockIdx.x;
  const float scale = __expf(temp[0]);

  // ---- stage x window into LDS (rows>=49 zeroed; pad 260 -> low conflicts) ----
  {
    const float* xb = x + (size_t)b * 12544;
    #pragma unroll
    for (int it = 0; it < 8; ++it){
      int fid = it*512 + tid;
      int row = fid >> 6, c4 = (fid & 63) << 2;
      float4 v = make_float4(0.f, 0.f, 0.f, 0.f);
      if (row < 49) v = *(const float4*)(xb + row*256 + c4);
      *(float4*)(xs + row*260 + c4) = v;
    }
  }
  __syncthreads();

  // ---- per-wave x A-fragments, plain bf16 (A[p][8*lg+j], k=kc*32+8*lg+j) ----
  U8 axh[8];
  {
    const int row = mt*16 + p;
    #pragma unroll
    for (int kc = 0; kc < 8; ++kc){
      float4 f0 = *(const float4*)(xs + row*260 + kc*32 + lg*8);
      float4 f1 = *(const float4*)(xs + row*260 + kc*32 + lg*8 + 4);
      float ff[8] = {f0.x,f0.y,f0.z,f0.w,f1.x,f1.y,f1.z,f1.w};
      #pragma unroll
      for (int j = 0; j < 8; ++j) axh[kc].e[j] = bf_hi(ff[j]);
    }
  }
  __syncthreads();   // xs dead; region free for Wstage

  const f32x4 z4 = {0.f, 0.f, 0.f, 0.f};
  f32x4 pacc[4][2];
  #pragma unroll
  for (int m2 = 0; m2 < 4; ++m2){ pacc[m2][0] = z4; pacc[m2][1] = z4; }

  for (int grp = 0; grp < 4; ++grp){
    const int h = grp*2 + hh;

    // ================= QKV GEMM (single-buffered Wstage via global_load_lds) =================
    f32x4 qa[2], ka[2], va[2];
    #pragma unroll
    for (int n = 0; n < 2; ++n){ qa[n] = z4; ka[n] = z4; va[n] = z4; }

    const u16* wg = wQ + (size_t)grp * 4 * 12288;
    #pragma unroll
    for (int kp = 0; kp < 4; ++kp){
      if (kp) __syncthreads();               // readers of previous chunk done
      {
        const char* src = (const char*)(wg + kp*12288) + tid*16;
        char* dst = (char*)LDSB + w*1024;    // wave-uniform base
        gload16(src,         dst);
        gload16(src + 8192,  dst + 8192);
        gload16(src + 16384, dst + 16384);
      }
      __syncthreads();                       // vmcnt(0) drain + barrier: chunk visible
      #pragma unroll
      for (int kcL = 0; kcL < 2; ++kcL){
        const int kc = kp*2 + kcL;
        #pragma unroll
        for (int tt = 0; tt < 3; ++tt){
          #pragma unroll
          for (int n = 0; n < 2; ++n){
            bf16x8 bh = *(const bf16x8*)(wst + kcL*6144 + (hh*6 + tt*2 + n)*512 + lane*8);
            f32x4 acc = (tt==0) ? qa[n] : (tt==1) ? ka[n] : va[n];
            acc = MFMA(axh[kc].v, bh, acc);
            if (tt==0) qa[n] = acc; else if (tt==1) ka[n] = acc; else va[n] = acc;
          }
        }
      }
    }

    // ---- bias + shift-mask prefetch (L2-hot, 64B segments) ----
    float bm[4][4];
    {
      const int wi = b & 63;
      #pragma unroll
      for (int n = 0; n < 4; ++n){
        #pragma unroll
        for (int r = 0; r < 4; ++r){
          const int i = mt*16 + lg*4 + r, j = n*16 + p;
          float v = 0.f;
          if (i < 49 && j < 49)
            v = biasws[h*2401 + i*49 + j] + mask[wi*2401 + i*49 + j];
          bm[n][r] = v;
        }
      }
    }

    // ---- bounce q,k (row-major [64][40]) and v (transposed [32][72]), bf16 ----
    #pragma unroll
    for (int n = 0; n < 2; ++n){
      #pragma unroll
      for (int r = 0; r < 4; ++r){
        const int token = mt*16 + lg*4 + r, dim = n*16 + p;
        const int qk = hh*2560 + token*40 + dim;
        qhi[qk] = bf_hi(qa[n][r]);
        khi[qk] = bf_hi(ka[n][r]);
        vthi[hh*2304 + dim*72 + token] = bf_hi(va[n][r]);
      }
    }
    __syncthreads();   // all QKV compute done; q/k/v visible; wst region free

    // ================= S = q k^T (scaled) + bias/mask, LSA diag =================
    U8 qf;
    qf.v = *(const bf16x8*)(qhi + hh*2560 + (mt*16 + p)*40 + lg*8);
    f32x4 sa[4];
    #pragma unroll
    for (int n = 0; n < 4; ++n) sa[n] = z4;
    #pragma unroll
    for (int n = 0; n < 4; ++n){
      bf16x8 kf = *(const bf16x8*)(khi + hh*2560 + (n*16 + p)*40 + lg*8);
      sa[n] = MFMA(qf.v, kf, sa[n]);
    }

    // ---- softmax over 64 cols (16 p-lanes x 4 n-tiles); 1/sum deferred into O ----
    float pr[4][4], rinv[4];
    #pragma unroll
    for (int r = 0; r < 4; ++r){
      const int i = mt*16 + lg*4 + r;
      float mx = -3.0e38f;
      #pragma unroll
      for (int n = 0; n < 4; ++n){
        const int j = n*16 + p;
        float s = sa[n][r]*scale + bm[n][r];
        if (j >= 49 || j == i) s = -3.0e38f;   // pad cols + LSA diagonal
        pr[n][r] = s;
        mx = fmaxf(mx, s);
      }
      mx = fmaxf(mx, __shfl_xor(mx, 1));
      mx = fmaxf(mx, __shfl_xor(mx, 2));
      mx = fmaxf(mx, __shfl_xor(mx, 4));
      mx = fmaxf(mx, __shfl_xor(mx, 8));
      float sum = 0.f;
      #pragma unroll
      for (int n = 0; n < 4; ++n){
        float e = __expf(pr[n][r] - mx);
        pr[n][r] = e; sum += e;
      }
      sum += __shfl_xor(sum, 1);
      sum += __shfl_xor(sum, 2);
      sum += __shfl_xor(sum, 4);
      sum += __shfl_xor(sum, 8);
      rinv[r] = 1.0f / sum;
    }

    // ---- P bounce (wave-private [16][72], bf16) ----
    #pragma unroll
    for (int n = 0; n < 4; ++n){
      #pragma unroll
      for (int r = 0; r < 4; ++r){
        Phi[w*1152 + (lg*4 + r)*72 + n*16 + p] = bf_hi(pr[n][r]);
      }
    }
    __syncthreads();

    // ================= O = P V =================
    f32x4 oa[2]; oa[0] = z4; oa[1] = z4;
    #pragma unroll
    for (int kc = 0; kc < 2; ++kc){
      bf16x8 pf = *(const bf16x8*)(Phi + w*1152 + p*72 + kc*32 + lg*8);
      #pragma unroll
      for (int n = 0; n < 2; ++n){
        bf16x8 vf = *(const bf16x8*)(vthi + hh*2304 + (n*16 + p)*72 + kc*32 + lg*8);
        oa[n] = MFMA(pf, vf, oa[n]);
      }
    }
    // ---- O bounce (apply deferred 1/sum), split hi/lo for accurate proj ----
    #pragma unroll
    for (int n = 0; n < 2; ++n){
      #pragma unroll
      for (int r = 0; r < 4; ++r){
        const int token = mt*16 + lg*4 + r, dim = n*16 + p;
        const int ok = hh*2560 + token*40 + dim;
        float ov = oa[n][r] * rinv[r];
        u16 oh_ = bf_hi(ov);
        ohi[ok] = oh_; olo[ok] = bf_hi(ov - bf_f(oh_));
      }
    }
    __syncthreads();

    // ================= proj accumulate (wave owns out cols [32w,32w+32)), split ========
    #pragma unroll
    for (int hc = 0; hc < 2; ++hc){
      const int hg = grp*2 + hc;
      U8 ah[4], al[4];
      #pragma unroll
      for (int m2 = 0; m2 < 4; ++m2){
        ah[m2].v = *(const bf16x8*)(ohi + hc*2560 + (m2*16 + p)*40 + lg*8);
        al[m2].v = *(const bf16x8*)(olo + hc*2560 + (m2*16 + p)*40 + lg*8);
      }
      #pragma unroll
      for (int n = 0; n < 2; ++n){
        bf16x8 bh = *(const bf16x8*)(wPH + ((size_t)(hg*16 + w*2 + n)*64 + lane)*8);
        bf16x8 bl = *(const bf16x8*)(wPL + ((size_t)(hg*16 + w*2 + n)*64 + lane)*8);
        #pragma unroll
        for (int m2 = 0; m2 < 4; ++m2){
          pacc[m2][n] = MFMA(ah[m2].v, bh, pacc[m2][n]);
          pacc[m2][n] = MFMA(ah[m2].v, bl, pacc[m2][n]);
          pacc[m2][n] = MFMA(al[m2].v, bh, pacc[m2][n]);
        }
      }
    }
    __syncthreads();   // obuf/Phi/Wstage regions free for next group
  }

  // ================= epilogue: + proj_b, store =================
  const float pb0 = proj_b[(w*2 + 0)*16 + p];
  const float pb1 = proj_b[(w*2 + 1)*16 + p];
  #pragma unroll
  for (int m2 = 0; m2 < 4; ++m2){
    #pragma unroll
    for (int r = 0; r < 4; ++r){
      const int row = m2*16 + lg*4 + r;
      if (row < 49){
        float* o = out + (size_t)b*12544 + row*256 + (w*2)*16 + p;
        o[0]  = pacc[m2][0][r] + pb0;
        o[16] = pacc[m2][1][r] + pb1;
      }
    }
  }
}

extern "C" void kernel_launch(void* const* d_in, const int* in_sizes, int n_in,
                              void* d_out, int out_size, void* d_ws, size_t ws_size,
                              hipStream_t stream)
{
  (void)in_sizes; (void)n_in; (void)out_size; (void)ws_size;
  const float* x      = (const float*)d_in[0];
  const float* mask   = (const float*)d_in[1];
  const float* qkv_w  = (const float*)d_in[2];
  const float* proj_w = (const float*)d_in[3];
  const float* proj_b = (const float*)d_in[4];
  const float* rpb    = (const float*)d_in[5];
  const float* temp   = (const float*)d_in[6];

  u16*   wQ     = (u16*)d_ws;
  u16*   wPH    = (u16*)((char*)d_ws + 393216);
  u16*   wPL    = (u16*)((char*)d_ws + 524288);
  float* biasws = (float*)((char*)d_ws + 655360);

  wa_pack<<<1100, 256, 0, stream>>>(qkv_w, proj_w, rpb, wQ, wPH, wPL, biasws);
  wa_main<<<4096, 512, 0, stream>>>(x, mask, temp, wQ, wPH, wPL, biasws, proj_b,
                                    (float*)d_out);
}

// Round 5
// 858.207 us; speedup vs baseline: 1.8290x; 1.2592x over previous
//
#include <hip/hip_runtime.h>

// Round 5: spill elimination + pipelined weight staging.
//  - x A-fragments moved VGPR -> LDS bf16 [64][264] (was the spill source: R4 had
//    64 arch VGPRs vs ~116 live -> ~470MB scratch R/W, the real 870us culprit)
//  - weight chunks 12KB, double-buffered, stage(k+1) || compute(k), 1 barrier/chunk
//  - LDS 62KB phase-overlaid, 2 blocks/CU; extra barriers after S and PV make the
//    Phi/o overlays race-free
// Numerics identical to R4 (passed, absmax 4.9e-4).

typedef unsigned short u16;
typedef unsigned int   u32;
typedef __attribute__((ext_vector_type(8))) short bf16x8;
typedef __attribute__((ext_vector_type(4))) float f32x4;

#define MFMA(a,b,c) __builtin_amdgcn_mfma_f32_16x16x32_bf16((a),(b),(c),0,0,0)

__device__ __forceinline__ u16 bf_hi(float f){
  u32 u = __float_as_uint(f);
  u += 0x7FFFu + ((u >> 16) & 1u);          // RNE to bf16
  return (u16)(u >> 16);
}
__device__ __forceinline__ float bf_f(u16 h){ return __uint_as_float(((u32)h) << 16); }

union U8 { bf16x8 v; u16 e[8]; };

// async global->LDS, 16B/lane: LDS dst = wave-uniform base + lane*16.
__device__ __forceinline__ void gload16(const void* g, void* l){
  __builtin_amdgcn_global_load_lds((const __attribute__((address_space(1))) void*)g,
                                   (__attribute__((address_space(3))) void*)l, 16, 0, 0);
}

// ---------------- weight/bias packing prologue ----------------
// ws layout (bytes):
//   [0, 393216)        wQ:  32 chunks of 12288B = (grp*8+kc) x [tile12][lane64][j8] bf16-hi
//   [393216, 524288)   wPH: [h8][nt16][lane64][8] u16 (proj hi)
//   [524288, 655360)   wPL: proj lo
//   [655360, 732192)   biasws: [8][49][49] f32
__global__ void wa_pack(const float* __restrict__ qkv_w, const float* __restrict__ proj_w,
                        const float* __restrict__ rpb,
                        u16* __restrict__ wQ, u16* __restrict__ wPH, u16* __restrict__ wPL,
                        float* __restrict__ biasws)
{
  int tid = blockIdx.x * 256 + threadIdx.x;
  if (tid < 196608){
    int chunk = tid / 6144, rem = tid % 6144;
    int tile = rem / 512, rem3 = rem % 512;
    int lane16 = rem3 & 15, j = (rem3 >> 4) & 7, lg = rem3 >> 7;
    int lane = lg*16 + lane16;
    int grp = chunk >> 3, kc = chunk & 7;
    int kg  = kc*32 + lg*8 + j;                              // contraction index (C)
    int hh = tile / 6, t6 = tile % 6, tt = t6 >> 1, nt = t6 & 1;
    int col = tt*256 + (grp*2+hh)*32 + nt*16 + lane16;       // d in [0,768)
    float f = qkv_w[kg*768 + col];
    wQ[chunk*6144 + tile*512 + lane*8 + j] = bf_hi(f);
  } else if (tid < 262144){
    int t1 = tid - 196608;
    int j = t1 & 7, lane = (t1>>3)&63, nt = (t1>>9)&15, h = t1>>13;
    int kg  = h*32 + (lane>>4)*8 + j;
    int col = nt*16 + (lane&15);
    float f = proj_w[kg*256 + col];
    u16 hi = bf_hi(f), lo = bf_hi(f - bf_f(hi));
    wPH[t1] = hi; wPL[t1] = lo;
  } else if (tid < 281352){
    int t2 = tid - 262144;
    int h = t2 / 2401, r = t2 % 2401;
    int i = r / 49, jj = r % 49;
    int ih = i/7, iw = i%7, jh = jj/7, jw = jj%7;
    int idx = (ih - jh + 6)*13 + (iw - jw + 6);
    biasws[t2] = rpb[idx*8 + h];
  }
}

// ---------------- main fused kernel ----------------
// LDS map (63488B, phase-overlaid; liveness separated by barriers):
//   [0,33792)       xbf [64][264] u16 (live whole kernel)
//   [33792,58368)   wst: 2 x 12288 weight slots (QKV phase)
//   [33792,44032)   qhi [2][64][40] (bounce -> S)
//   [44032,54272)   khi [2][64][40] (bounce -> S)
//   [54272,63488)   vthi [2][32][72] (bounce -> PV)
//   [33792,52224)   Phi [8][16][72] (P-bounce -> PV; after S-barrier)
//   [33792,54272)   ohi/olo [2][64][40] x2 (O-bounce -> proj; after PV-barrier)
__global__ __launch_bounds__(512, 4) void wa_main(
    const float* __restrict__ x, const float* __restrict__ mask,
    const float* __restrict__ temp,
    const u16* __restrict__ wQ, const u16* __restrict__ wPH, const u16* __restrict__ wPL,
    const float* __restrict__ biasws, const float* __restrict__ proj_b,
    float* __restrict__ out)
{
  __shared__ __align__(16) char LDSB[63488];
  u16* xbf  = (u16*)LDSB;                    // [64][264]
  u16* wst  = (u16*)(LDSB + 33792);          // 2 slots x 6144 u16
  u16* qhi  = (u16*)(LDSB + 33792);          // [2][64][40]
  u16* khi  = (u16*)(LDSB + 44032);
  u16* vthi = (u16*)(LDSB + 54272);          // [2][32][72] (v transposed)
  u16* Phi  = (u16*)(LDSB + 33792);          // [8][16][72]
  u16* ohi  = (u16*)(LDSB + 33792);          // [2][64][40]
  u16* olo  = (u16*)(LDSB + 44032);

  const int tid = threadIdx.x;
  const int w = tid >> 6, lane = tid & 63;
  const int p = lane & 15, lg = lane >> 4;
  const int mt = w & 3;        // row-tile owned
  const int hh = w >> 2;       // head-in-group owned
  const int b  = blockIdx.x;
  const float scale = __expf(temp[0]);

  // ---- stage x window into LDS as bf16 (rows>=49 zeroed) ----
  {
    const float* xb = x + (size_t)b * 12544;
    #pragma unroll
    for (int it = 0; it < 8; ++it){
      int fid = it*512 + tid;
      int row = fid >> 6, c4 = (fid & 63) << 2;
      float4 v = make_float4(0.f, 0.f, 0.f, 0.f);
      if (row < 49) v = *(const float4*)(xb + row*256 + c4);
      union { u16 e[4]; uint2 u; } t;
      t.e[0] = bf_hi(v.x); t.e[1] = bf_hi(v.y);
      t.e[2] = bf_hi(v.z); t.e[3] = bf_hi(v.w);
      *(uint2*)(xbf + row*264 + c4) = t.u;   // 8B store, 8B-aligned
    }
  }
  // stage grp0 chunk0 into slot0 (overlaps x staging; drained by same barrier)
  {
    const char* cb = (const char*)wQ;
    char* db = (char*)wst;
    gload16(cb + tid*16, db + w*1024);
    if (w < 4) gload16(cb + 8192 + tid*16, db + 8192 + w*1024);
  }
  __syncthreads();

  const f32x4 z4 = {0.f, 0.f, 0.f, 0.f};
  f32x4 pacc[4][2];
  #pragma unroll
  for (int m2 = 0; m2 < 4; ++m2){ pacc[m2][0] = z4; pacc[m2][1] = z4; }

  for (int grp = 0; grp < 4; ++grp){
    const int h = grp*2 + hh;
    const u16* wg = wQ + (size_t)grp * 49152;   // 8 chunks x 6144 u16

    if (grp){   // stage chunk0 (slot0); exposed, but L2-hot
      const char* cb = (const char*)wg;
      char* db = (char*)wst;
      gload16(cb + tid*16, db + w*1024);
      if (w < 4) gload16(cb + 8192 + tid*16, db + 8192 + w*1024);
      __syncthreads();
    }

    // ---- bias + shift-mask prefetch (issues early, consumed in softmax) ----
    float bm[4][4];
    {
      const int wi = b & 63;
      #pragma unroll
      for (int n = 0; n < 4; ++n){
        #pragma unroll
        for (int r = 0; r < 4; ++r){
          const int i = mt*16 + lg*4 + r, j = n*16 + p;
          float v = 0.f;
          if (i < 49 && j < 49)
            v = biasws[h*2401 + i*49 + j] + mask[wi*2401 + i*49 + j];
          bm[n][r] = v;
        }
      }
    }

    // ================= QKV GEMM: stage(k+1) || compute(k), dbuf slots ==========
    f32x4 qa[2], ka[2], va[2];
    #pragma unroll
    for (int n = 0; n < 2; ++n){ qa[n] = z4; ka[n] = z4; va[n] = z4; }

    #pragma unroll
    for (int kc = 0; kc < 8; ++kc){
      if (kc < 7){
        const char* cb = (const char*)(wg + (kc+1)*6144);
        char* db = (char*)wst + ((kc+1)&1)*12288;
        gload16(cb + tid*16, db + w*1024);
        if (w < 4) gload16(cb + 8192 + tid*16, db + 8192 + w*1024);
      }
      __builtin_amdgcn_sched_barrier(0);     // pin prefetch issue before compute
      U8 ax;
      ax.v = *(const bf16x8*)(xbf + (mt*16 + p)*264 + kc*32 + lg*8);
      const u16* ws0 = wst + (kc & 1)*6144;
      #pragma unroll
      for (int tt = 0; tt < 3; ++tt){
        #pragma unroll
        for (int n = 0; n < 2; ++n){
          bf16x8 bh = *(const bf16x8*)(ws0 + (hh*6 + tt*2 + n)*512 + lane*8);
          f32x4 acc = (tt==0) ? qa[n] : (tt==1) ? ka[n] : va[n];
          acc = MFMA(ax.v, bh, acc);
          if (tt==0) qa[n] = acc; else if (tt==1) ka[n] = acc; else va[n] = acc;
        }
      }
      __syncthreads();   // retires slot reads; publishes next chunk
    }

    // ---- bounce q,k ([64][40]) and v^T ([32][72]); wst dead ----
    #pragma unroll
    for (int n = 0; n < 2; ++n){
      #pragma unroll
      for (int r = 0; r < 4; ++r){
        const int token = mt*16 + lg*4 + r, dim = n*16 + p;
        const int qk = hh*2560 + token*40 + dim;
        qhi[qk] = bf_hi(qa[n][r]);
        khi[qk] = bf_hi(ka[n][r]);
        vthi[hh*2304 + dim*72 + token] = bf_hi(va[n][r]);
      }
    }
    __syncthreads();

    // ================= S = q k^T (scaled) + bias/mask, LSA diag ==============
    U8 qf;
    qf.v = *(const bf16x8*)(qhi + hh*2560 + (mt*16 + p)*40 + lg*8);
    f32x4 sa[4];
    #pragma unroll
    for (int n = 0; n < 4; ++n) sa[n] = z4;
    #pragma unroll
    for (int n = 0; n < 4; ++n){
      bf16x8 kf = *(const bf16x8*)(khi + hh*2560 + (n*16 + p)*40 + lg*8);
      sa[n] = MFMA(qf.v, kf, sa[n]);
    }

    // ---- softmax over 64 cols; 1/sum deferred into O ----
    float pr[4][4], rinv[4];
    #pragma unroll
    for (int r = 0; r < 4; ++r){
      const int i = mt*16 + lg*4 + r;
      float mx = -3.0e38f;
      #pragma unroll
      for (int n = 0; n < 4; ++n){
        const int j = n*16 + p;
        float s = sa[n][r]*scale + bm[n][r];
        if (j >= 49 || j == i) s = -3.0e38f;   // pad cols + LSA diagonal
        pr[n][r] = s;
        mx = fmaxf(mx, s);
      }
      mx = fmaxf(mx, __shfl_xor(mx, 1));
      mx = fmaxf(mx, __shfl_xor(mx, 2));
      mx = fmaxf(mx, __shfl_xor(mx, 4));
      mx = fmaxf(mx, __shfl_xor(mx, 8));
      float sum = 0.f;
      #pragma unroll
      for (int n = 0; n < 4; ++n){
        float e = __expf(pr[n][r] - mx);
        pr[n][r] = e; sum += e;
      }
      sum += __shfl_xor(sum, 1);
      sum += __shfl_xor(sum, 2);
      sum += __shfl_xor(sum, 4);
      sum += __shfl_xor(sum, 8);
      rinv[r] = 1.0f / sum;
    }
    __syncthreads();   // retires cross-wave q/k reads; Phi may overlay them

    // ---- P bounce (wave-private [16][72], bf16; over q/k region) ----
    #pragma unroll
    for (int n = 0; n < 4; ++n){
      #pragma unroll
      for (int r = 0; r < 4; ++r){
        Phi[w*1152 + (lg*4 + r)*72 + n*16 + p] = bf_hi(pr[n][r]);
      }
    }
    __syncthreads();

    // ================= O = P V =================
    f32x4 oa[2]; oa[0] = z4; oa[1] = z4;
    #pragma unroll
    for (int kc = 0; kc < 2; ++kc){
      bf16x8 pf = *(const bf16x8*)(Phi + w*1152 + p*72 + kc*32 + lg*8);
      #pragma unroll
      for (int n = 0; n < 2; ++n){
        bf16x8 vf = *(const bf16x8*)(vthi + hh*2304 + (n*16 + p)*72 + kc*32 + lg*8);
        oa[n] = MFMA(pf, vf, oa[n]);
      }
    }
    __syncthreads();   // retires cross-wave Phi/v reads; o may overlay them

    // ---- O bounce (apply deferred 1/sum), split hi/lo for accurate proj ----
    #pragma unroll
    for (int n = 0; n < 2; ++n){
      #pragma unroll
      for (int r = 0; r < 4; ++r){
        const int token = mt*16 + lg*4 + r, dim = n*16 + p;
        const int ok = hh*2560 + token*40 + dim;
        float ov = oa[n][r] * rinv[r];
        u16 oh_ = bf_hi(ov);
        ohi[ok] = oh_; olo[ok] = bf_hi(ov - bf_f(oh_));
      }
    }
    __syncthreads();

    // ================= proj accumulate (wave owns out cols [32w,32w+32)) =====
    #pragma unroll
    for (int hc = 0; hc < 2; ++hc){
      const int hg = grp*2 + hc;
      U8 ah[4], al[4];
      #pragma unroll
      for (int m2 = 0; m2 < 4; ++m2){
        ah[m2].v = *(const bf16x8*)(ohi + hc*2560 + (m2*16 + p)*40 + lg*8);
        al[m2].v = *(const bf16x8*)(olo + hc*2560 + (m2*16 + p)*40 + lg*8);
      }
      #pragma unroll
      for (int n = 0; n < 2; ++n){
        bf16x8 bh = *(const bf16x8*)(wPH + ((size_t)(hg*16 + w*2 + n)*64 + lane)*8);
        bf16x8 bl = *(const bf16x8*)(wPL + ((size_t)(hg*16 + w*2 + n)*64 + lane)*8);
        #pragma unroll
        for (int m2 = 0; m2 < 4; ++m2){
          pacc[m2][n] = MFMA(ah[m2].v, bh, pacc[m2][n]);
          pacc[m2][n] = MFMA(ah[m2].v, bl, pacc[m2][n]);
          pacc[m2][n] = MFMA(al[m2].v, bh, pacc[m2][n]);
        }
      }
    }
    __syncthreads();   // retires o reads; next grp may stage weights over them
  }

  // ================= epilogue: + proj_b, store =================
  const float pb0 = proj_b[(w*2 + 0)*16 + p];
  const float pb1 = proj_b[(w*2 + 1)*16 + p];
  #pragma unroll
  for (int m2 = 0; m2 < 4; ++m2){
    #pragma unroll
    for (int r = 0; r < 4; ++r){
      const int row = m2*16 + lg*4 + r;
      if (row < 49){
        float* o = out + (size_t)b*12544 + row*256 + (w*2)*16 + p;
        o[0]  = pacc[m2][0][r] + pb0;
        o[16] = pacc[m2][1][r] + pb1;
      }
    }
  }
}

extern "C" void kernel_launch(void* const* d_in, const int* in_sizes, int n_in,
                              void* d_out, int out_size, void* d_ws, size_t ws_size,
                              hipStream_t stream)
{
  (void)in_sizes; (void)n_in; (void)out_size; (void)ws_size;
  const float* x      = (const float*)d_in[0];
  const float* mask   = (const float*)d_in[1];
  const float* qkv_w  = (const float*)d_in[2];
  const float* proj_w = (const float*)d_in[3];
  const float* proj_b = (const float*)d_in[4];
  const float* rpb    = (const float*)d_in[5];
  const float* temp   = (const float*)d_in[6];

  u16*   wQ     = (u16*)d_ws;
  u16*   wPH    = (u16*)((char*)d_ws + 393216);
  u16*   wPL    = (u16*)((char*)d_ws + 524288);
  float* biasws = (float*)((char*)d_ws + 655360);

  wa_pack<<<1100, 256, 0, stream>>>(qkv_w, proj_w, rpb, wQ, wPH, wPL, biasws);
  wa_main<<<4096, 512, 0, stream>>>(x, mask, temp, wQ, wPH, wPL, biasws, proj_b,
                                    (float*)d_out);
}